// Round 1
// baseline (961.913 us; speedup 1.0000x reference)
//
#include <hip/hip_runtime.h>

#define Bq   16
#define Cq   16
#define VIN  16000
#define V1q  16384
#define V2q  4096
#define Kq   16
#define F1q  32
#define F2q  64
#define FCO  512
#define FCIN 65536

// ---------------- BatchNorm stats (two stage) ----------------
__global__ void bn_part(const float* __restrict__ x, float* __restrict__ part) {
    int c  = blockIdx.y;           // channel
    int bx = blockIdx.x;           // 0..63
    int b  = bx >> 2;              // 0..15
    int vc = bx & 3;               // quarter of the 16000 vertices
    const float* p = x + (size_t)(b * Cq + c) * VIN + vc * 4000;
    float s = 0.f, s2 = 0.f;
    for (int v = threadIdx.x; v < 4000; v += 256) {
        float val = p[v];
        s += val; s2 += val * val;
    }
    for (int o = 32; o; o >>= 1) { s += __shfl_down(s, o); s2 += __shfl_down(s2, o); }
    __shared__ float ls[4], ls2[4];
    int wid = threadIdx.x >> 6;
    if ((threadIdx.x & 63) == 0) { ls[wid] = s; ls2[wid] = s2; }
    __syncthreads();
    if (threadIdx.x == 0) {
        s = ls[0] + ls[1] + ls[2] + ls[3];
        s2 = ls2[0] + ls2[1] + ls2[2] + ls2[3];
        part[(c * 64 + bx) * 2]     = s;
        part[(c * 64 + bx) * 2 + 1] = s2;
    }
}

__global__ void bn_final(const float* __restrict__ part, float* __restrict__ mean_rstd) {
    int t = threadIdx.x;           // 256 threads: c = t/16, j = t%16
    int c = t >> 4, j = t & 15;
    float s = 0.f, s2 = 0.f;
    for (int i = 0; i < 4; i++) {
        s  += part[(c * 64 + j * 4 + i) * 2];
        s2 += part[(c * 64 + j * 4 + i) * 2 + 1];
    }
    for (int o = 8; o; o >>= 1) { s += __shfl_down(s, o, 16); s2 += __shfl_down(s2, o, 16); }
    if (j == 0) {
        float m  = s / 256000.f;
        float var = s2 / 256000.f - m * m;
        mean_rstd[c]      = m;
        mean_rstd[16 + c] = rsqrtf(var + 1e-5f);
    }
}

// ---------------- inverse permutation ----------------
__global__ void build_iperm(const int* __restrict__ perm, int* __restrict__ iperm) {
    int v = blockIdx.x * 256 + threadIdx.x;
    if (v < V1q) iperm[perm[v]] = v;
}

// ------- normalize + transpose (B,C,V)->(V, C*B) + permute scatter -------
__global__ void norm_transpose_scatter(const float* __restrict__ x,
                                       const float* __restrict__ mean_rstd,
                                       const int* __restrict__ iperm,
                                       float* __restrict__ X0) {
    __shared__ float tile[256][33];    // [dest col d][u local]
    int u0 = blockIdx.x * 32;
    int t  = threadIdx.x;
    int jj = t & 31, half = t >> 5;    // 8 source rows per iteration
    for (int rr = 0; rr < 32; rr++) {
        int s = rr * 8 + half;         // source row = b*16 + c
        int c = s & 15;
        float val = x[(size_t)s * VIN + u0 + jj];
        val = (val - mean_rstd[c]) * mean_rstd[16 + c];
        int d = ((s & 15) << 4) | (s >> 4);   // dest col = c*16 + b
        tile[d][jj] = val;
    }
    __syncthreads();
    for (int j = 0; j < 32; j++) {
        int tv = iperm[u0 + j];
        X0[(size_t)tv * 256 + t] = tile[t][j];
    }
}

// ---------------- weight transposes ----------------
__global__ void transpose_w1(const float* __restrict__ w1, float* __restrict__ w1t) {
    int i = blockIdx.x * 256 + threadIdx.x;   // 8192 = K*C*F1
    int f = i & 31, c = (i >> 5) & 15, k = i >> 9;
    w1t[i] = w1[f * 256 + c * 16 + k];
}
__global__ void transpose_w2(const float* __restrict__ w2, float* __restrict__ w2t) {
    int i = blockIdx.x * 256 + threadIdx.x;   // 32768 = K*F1*F2
    int f2 = i & 63, f = (i >> 6) & 31, k = i >> 11;
    w2t[i] = w2[f2 * 512 + f * 16 + k];
}

// ---------------- Chebyshev SpMM: out = scale*L*prev - (sub? prev2 : 0) ----------------
__global__ void spmm_cheb(const float* __restrict__ prev,
                          const float* __restrict__ prev2,
                          float* __restrict__ out,
                          const int* __restrict__ cols,
                          const float* __restrict__ vals,
                          int width, float scale, int sub) {
    int lane = threadIdx.x & 63;
    int rgrp = threadIdx.x >> 6;               // 4 rows per block
    int r  = blockIdx.x * 4 + rgrp;
    int cb = blockIdx.y * 64 + lane;
    const int*   cp = cols + r * 16;
    const float* vp = vals + r * 16;
    float acc = 0.f;
#pragma unroll
    for (int j = 0; j < 16; j++) {
        acc += vp[j] * prev[(size_t)cp[j] * width + cb];
    }
    float o = scale * acc;
    if (sub) o -= prev2[(size_t)r * width + cb];
    out[(size_t)r * width + cb] = o;
}

// ------- GEMM1: (B*V1, C*K)@(C*K, F1) + bias + relu + pool4 -> XS2 slice0 -------
__launch_bounds__(256)
__global__ void gemm1_pool(const float* __restrict__ XS1,   // [K][V1][256]
                           const float* __restrict__ w1t,   // [K][16][32]
                           const float* __restrict__ b1,
                           float* __restrict__ P1) {        // [V2][512]
    __shared__ float wlds[8192];
    __shared__ float alds[8][264];
    __shared__ float ylds[8][516];
    int t = threadIdx.x;
    for (int i = t; i < 8192; i += 256) wlds[i] = w1t[i];
    int f = t >> 3, v = t & 7;
    int v0 = blockIdx.x * 8;
    float acc[16];
#pragma unroll
    for (int b = 0; b < 16; b++) acc[b] = 0.f;
    for (int k = 0; k < Kq; k++) {
        __syncthreads();
        {
            int vr = t >> 5;
            int base = (t & 31) * 8;
            const float* src = XS1 + ((size_t)k * V1q + v0 + vr) * 256 + base;
            *(float4*)&alds[vr][base]     = *(const float4*)(src);
            *(float4*)&alds[vr][base + 4] = *(const float4*)(src + 4);
        }
        __syncthreads();
#pragma unroll
        for (int c = 0; c < 16; c++) {
            float w = wlds[(k * 16 + c) * 32 + f];
            const float4* ap = (const float4*)&alds[v][c * 16];
#pragma unroll
            for (int q = 0; q < 4; q++) {
                float4 a = ap[q];
                acc[q * 4 + 0] += w * a.x;
                acc[q * 4 + 1] += w * a.y;
                acc[q * 4 + 2] += w * a.z;
                acc[q * 4 + 3] += w * a.w;
            }
        }
    }
    float bias = b1[f];
    __syncthreads();
#pragma unroll
    for (int q = 0; q < 4; q++) {
        float4 y;
        y.x = fmaxf(acc[q * 4 + 0] + bias, 0.f);
        y.y = fmaxf(acc[q * 4 + 1] + bias, 0.f);
        y.z = fmaxf(acc[q * 4 + 2] + bias, 0.f);
        y.w = fmaxf(acc[q * 4 + 3] + bias, 0.f);
        *(float4*)&ylds[v][f * 16 + q * 4] = y;
    }
    __syncthreads();
    int u0 = blockIdx.x * 2;
    for (int p = t; p < 512; p += 256) {
#pragma unroll
        for (int ul = 0; ul < 2; ul++) {
            float m = ylds[ul * 4 + 0][p];
            m = fmaxf(m, ylds[ul * 4 + 1][p]);
            m = fmaxf(m, ylds[ul * 4 + 2][p]);
            m = fmaxf(m, ylds[ul * 4 + 3][p]);
            P1[(size_t)(u0 + ul) * 512 + p] = m;
        }
    }
}

// ------- GEMM2: (B*V2, F1*K)@(F1*K, F2) + bias + relu + pool4 -> P2alt -------
__launch_bounds__(256)
__global__ void gemm2_pool(const float* __restrict__ XS2,   // [K][V2][512]
                           const float* __restrict__ w2t,   // [K][32][64]
                           const float* __restrict__ b2,
                           float* __restrict__ P2a) {       // [1024][1024] = [u][f2*16+b]
    __shared__ float wlds[2048];
    __shared__ float alds[4][520];
    __shared__ float ylds[4][1032];
    int t = threadIdx.x;
    int f2 = t >> 2, v = t & 3;
    int v0 = blockIdx.x * 4;
    float acc[16];
#pragma unroll
    for (int b = 0; b < 16; b++) acc[b] = 0.f;
    for (int k = 0; k < Kq; k++) {
        __syncthreads();
        for (int i = t; i < 2048; i += 256) wlds[i] = w2t[k * 2048 + i];
        {
            int vr = t >> 6;
            int base = (t & 63) * 8;
            const float* src = XS2 + ((size_t)k * V2q + v0 + vr) * 512 + base;
            *(float4*)&alds[vr][base]     = *(const float4*)(src);
            *(float4*)&alds[vr][base + 4] = *(const float4*)(src + 4);
        }
        __syncthreads();
#pragma unroll
        for (int ff = 0; ff < 32; ff++) {
            float w = wlds[ff * 64 + f2];
            const float4* ap = (const float4*)&alds[v][ff * 16];
#pragma unroll
            for (int q = 0; q < 4; q++) {
                float4 a = ap[q];
                acc[q * 4 + 0] += w * a.x;
                acc[q * 4 + 1] += w * a.y;
                acc[q * 4 + 2] += w * a.z;
                acc[q * 4 + 3] += w * a.w;
            }
        }
    }
    float bias = b2[f2];
    __syncthreads();
#pragma unroll
    for (int q = 0; q < 4; q++) {
        float4 y;
        y.x = fmaxf(acc[q * 4 + 0] + bias, 0.f);
        y.y = fmaxf(acc[q * 4 + 1] + bias, 0.f);
        y.z = fmaxf(acc[q * 4 + 2] + bias, 0.f);
        y.w = fmaxf(acc[q * 4 + 3] + bias, 0.f);
        *(float4*)&ylds[v][f2 * 16 + q * 4] = y;
    }
    __syncthreads();
    int u = blockIdx.x;
    for (int p = t; p < 1024; p += 256) {
        float m = ylds[0][p];
        m = fmaxf(m, ylds[1][p]);
        m = fmaxf(m, ylds[2][p]);
        m = fmaxf(m, ylds[3][p]);
        P2a[(size_t)u * 1024 + p] = m;
    }
}

// ------- transpose P2alt[u][f2*16+b] -> P2flat[b*64+f2][u] (= flatten (B,F2,1024)) -------
__global__ void transpose_p2(const float* __restrict__ P2a, float* __restrict__ P2f) {
    __shared__ float tile[32][33];
    int u0  = blockIdx.x * 32;
    int fb0 = blockIdx.y * 32;
    int t = threadIdx.x;
    int col = t & 31, rowg = t >> 5;
    for (int i = 0; i < 4; i++) {
        int ul = rowg + i * 8;
        tile[ul][col] = P2a[(size_t)(u0 + ul) * 1024 + fb0 + col];
    }
    __syncthreads();
    for (int i = 0; i < 4; i++) {
        int jl = rowg + i * 8;
        int fb = fb0 + jl;
        int bf = (fb & 15) * 64 + (fb >> 4);
        P2f[(size_t)bf * 1024 + u0 + col] = tile[col][jl];
    }
}

// ---------------- FC ----------------
__global__ void fc_init(const float* __restrict__ b, float* __restrict__ out) {
    int i = blockIdx.x * 256 + threadIdx.x;   // 8192
    out[i] = b[i & 511];
}

__launch_bounds__(256)
__global__ void fc1k(const float* __restrict__ P2f, const float* __restrict__ W,
                     float* __restrict__ out) {
    __shared__ float plds[16][260];
    __shared__ float wlds[32][260];
    int t = threadIdx.x;
    int o0 = blockIdx.x * 32;
    int cbase = blockIdx.y * 2048;
    int b = t & 15, og = t >> 4;
    float acc0 = 0.f, acc1 = 0.f;
    for (int ch = 0; ch < 8; ch++) {
        int cc = cbase + ch * 256;
        __syncthreads();
        {
            int row = t >> 4, base = (t & 15) * 16;
            const float* src = P2f + (size_t)row * FCIN + cc + base;
            for (int q = 0; q < 16; q += 4)
                *(float4*)&plds[row][base + q] = *(const float4*)(src + q);
        }
        {
            int row = t >> 3, base = (t & 7) * 32;
            const float* src = W + (size_t)(o0 + row) * FCIN + cc + base;
            for (int q = 0; q < 32; q += 4)
                *(float4*)&wlds[row][base + q] = *(const float4*)(src + q);
        }
        __syncthreads();
#pragma unroll
        for (int j = 0; j < 256; j += 4) {
            float4 a  = *(const float4*)&plds[b][j];
            float4 wa = *(const float4*)&wlds[og][j];
            float4 wb = *(const float4*)&wlds[og + 16][j];
            acc0 += a.x * wa.x + a.y * wa.y + a.z * wa.z + a.w * wa.w;
            acc1 += a.x * wb.x + a.y * wb.y + a.z * wb.z + a.w * wb.w;
        }
    }
    atomicAdd(&out[b * 512 + o0 + og], acc0);
    atomicAdd(&out[b * 512 + o0 + og + 16], acc1);
}

extern "C" void kernel_launch(void* const* d_in, const int* in_sizes, int n_in,
                              void* d_out, int out_size, void* d_ws, size_t ws_size,
                              hipStream_t stream) {
    const float* x       = (const float*)d_in[0];
    const int*   perm    = (const int*)d_in[1];
    const int*   l1_cols = (const int*)d_in[3];
    const float* l1_vals = (const float*)d_in[4];
    const int*   l2_cols = (const int*)d_in[6];
    const float* l2_vals = (const float*)d_in[7];
    const float* w1      = (const float*)d_in[8];
    const float* b1      = (const float*)d_in[9];
    const float* w2      = (const float*)d_in[10];
    const float* b2      = (const float*)d_in[11];
    const float* fcw     = (const float*)d_in[12];
    const float* fcb     = (const float*)d_in[13];
    float* out = (float*)d_out;

    char* wsb = (char*)d_ws;
    size_t off = 0;
    auto alloc = [&](size_t bytes) -> void* {
        void* p = wsb + off;
        off += (bytes + 255) & ~(size_t)255;
        return p;
    };
    float* mean_rstd = (float*)alloc(32 * 4);
    float* bnpart    = (float*)alloc(16 * 64 * 2 * 4);
    int*   iperm     = (int*)alloc((size_t)V1q * 4);
    float* w1t       = (float*)alloc(8192 * 4);
    float* w2t       = (float*)alloc(32768 * 4);
    float* XS1       = (float*)alloc((size_t)Kq * V1q * 256 * 4);
    float* XS2       = (float*)alloc((size_t)Kq * V2q * 512 * 4);
    float* P2a       = (float*)alloc((size_t)1024 * 1024 * 4);
    float* P2f       = (float*)alloc((size_t)16 * FCIN * 4);
    (void)ws_size; (void)in_sizes; (void)n_in; (void)out_size;

    const size_t S1 = (size_t)V1q * 256;
    const size_t S2 = (size_t)V2q * 512;

    // BatchNorm stats
    bn_part<<<dim3(64, 16), 256, 0, stream>>>(x, bnpart);
    bn_final<<<1, 256, 0, stream>>>(bnpart, mean_rstd);
    // inverse permutation; zero padded rows of X0 (= XS1 slice 0)
    build_iperm<<<V1q / 256, 256, 0, stream>>>(perm, iperm);
    hipMemsetAsync(XS1, 0, S1 * 4, stream);
    norm_transpose_scatter<<<500, 256, 0, stream>>>(x, mean_rstd, iperm, XS1);
    // weight transposes
    transpose_w1<<<32, 256, 0, stream>>>(w1, w1t);
    transpose_w2<<<128, 256, 0, stream>>>(w2, w2t);
    // Chebyshev levels, conv1
    spmm_cheb<<<dim3(V1q / 4, 4), 256, 0, stream>>>(XS1, XS1, XS1 + S1, l1_cols, l1_vals, 256, 1.f, 0);
    for (int k = 2; k < Kq; k++)
        spmm_cheb<<<dim3(V1q / 4, 4), 256, 0, stream>>>(XS1 + (size_t)(k - 1) * S1, XS1 + (size_t)(k - 2) * S1,
                                                        XS1 + (size_t)k * S1, l1_cols, l1_vals, 256, 2.f, 1);
    // channel mix + relu + pool4 -> XS2 slice 0
    gemm1_pool<<<V1q / 8, 256, 0, stream>>>(XS1, w1t, b1, XS2);
    // Chebyshev levels, conv2
    spmm_cheb<<<dim3(V2q / 4, 8), 256, 0, stream>>>(XS2, XS2, XS2 + S2, l2_cols, l2_vals, 512, 1.f, 0);
    for (int k = 2; k < Kq; k++)
        spmm_cheb<<<dim3(V2q / 4, 8), 256, 0, stream>>>(XS2 + (size_t)(k - 1) * S2, XS2 + (size_t)(k - 2) * S2,
                                                        XS2 + (size_t)k * S2, l2_cols, l2_vals, 512, 2.f, 1);
    // channel mix + relu + pool4
    gemm2_pool<<<V2q / 4, 256, 0, stream>>>(XS2, w2t, b2, P2a);
    // layout for FC
    transpose_p2<<<dim3(32, 32), 256, 0, stream>>>(P2a, P2f);
    // FC
    fc_init<<<32, 256, 0, stream>>>(fcb, out);
    fc1k<<<dim3(16, 32), 256, 0, stream>>>(P2f, fcw, out);
}

// Round 2
// 702.593 us; speedup vs baseline: 1.3691x; 1.3691x over previous
//
#include <hip/hip_runtime.h>

#define VIN  16000
#define V1q  16384
#define V2q  4096
#define Kq   16
#define F1q  32
#define F2q  64
#define FCIN 65536

typedef unsigned short u16;
typedef __attribute__((ext_vector_type(8))) short short8;
typedef __attribute__((ext_vector_type(4))) float f32x4;

__device__ __forceinline__ float bf2f(u16 v) { return __uint_as_float((unsigned)v << 16); }
__device__ __forceinline__ u16 f2bf(float f) {
    unsigned u = __float_as_uint(f);
    return (u16)((u + 0x7fffu + ((u >> 16) & 1u)) >> 16);
}

// ---------------- BatchNorm stats (two stage) ----------------
__global__ void bn_part(const float* __restrict__ x, float* __restrict__ part) {
    int c  = blockIdx.y;
    int bx = blockIdx.x;           // 0..63
    int b  = bx >> 2;
    int vc = bx & 3;
    const float* p = x + (size_t)(b * 16 + c) * VIN + vc * 4000;
    float s = 0.f, s2 = 0.f;
    for (int v = threadIdx.x; v < 4000; v += 256) {
        float val = p[v];
        s += val; s2 += val * val;
    }
    for (int o = 32; o; o >>= 1) { s += __shfl_down(s, o); s2 += __shfl_down(s2, o); }
    __shared__ float ls[4], ls2[4];
    int wid = threadIdx.x >> 6;
    if ((threadIdx.x & 63) == 0) { ls[wid] = s; ls2[wid] = s2; }
    __syncthreads();
    if (threadIdx.x == 0) {
        s = ls[0] + ls[1] + ls[2] + ls[3];
        s2 = ls2[0] + ls2[1] + ls2[2] + ls2[3];
        part[(c * 64 + bx) * 2]     = s;
        part[(c * 64 + bx) * 2 + 1] = s2;
    }
}

__global__ void bn_final(const float* __restrict__ part, float* __restrict__ mean_rstd) {
    int t = threadIdx.x;
    int c = t >> 4, j = t & 15;
    float s = 0.f, s2 = 0.f;
    for (int i = 0; i < 4; i++) {
        s  += part[(c * 64 + j * 4 + i) * 2];
        s2 += part[(c * 64 + j * 4 + i) * 2 + 1];
    }
    for (int o = 8; o; o >>= 1) { s += __shfl_down(s, o, 16); s2 += __shfl_down(s2, o, 16); }
    if (j == 0) {
        float m  = s / 256000.f;
        float var = s2 / 256000.f - m * m;
        mean_rstd[c]      = m;
        mean_rstd[16 + c] = rsqrtf(var + 1e-5f);
    }
}

// ---------------- inverse permutation ----------------
__global__ void build_iperm(const int* __restrict__ perm, int* __restrict__ iperm) {
    int v = blockIdx.x * 256 + threadIdx.x;
    if (v < V1q) iperm[perm[v]] = v;
}

// ------- normalize + transpose + permute scatter, bf16, fragment column order -------
// X0 row v (256 cols): value (b,c) stored at col' = (c>>3)*128 + b*8 + (c&7)
__global__ void norm_transpose_scatter(const float* __restrict__ x,
                                       const float* __restrict__ mean_rstd,
                                       const int* __restrict__ iperm,
                                       u16* __restrict__ X0) {
    __shared__ u16 tile[256][33];
    int u0 = blockIdx.x * 32;
    int t  = threadIdx.x;
    int jj = t & 31, half = t >> 5;
    for (int rr = 0; rr < 32; rr++) {
        int s = rr * 8 + half;           // source row = b*16 + c
        int c = s & 15, b = s >> 4;
        float val = x[(size_t)s * VIN + u0 + jj];
        val = (val - mean_rstd[c]) * mean_rstd[16 + c];
        int d = ((c >> 3) << 7) | (b << 3) | (c & 7);
        tile[d][jj] = f2bf(val);
    }
    __syncthreads();
    for (int j = 0; j < 32; j++) {
        int tv = iperm[u0 + j];
        X0[(size_t)tv * 256 + t] = tile[t][j];
    }
}

// ---------------- weight packing into MFMA B-fragment order ----------------
// B1p[((s*2+nf)*64 + l)*8 + j] = w1[f][c*16+k], f=nf*16+(l&15), q=l>>4,
//   k = s*2 + (q>>1), c = (q&1)*8 + j
__global__ void pack_w1(const float* __restrict__ w1, u16* __restrict__ B1p) {
    int i = blockIdx.x * 256 + threadIdx.x;   // 8192
    int j = i & 7, l = (i >> 3) & 63, nf = (i >> 9) & 1, s = i >> 10;
    int q = l >> 4;
    int k = s * 2 + (q >> 1);
    int c = (q & 1) * 8 + j;
    int f = nf * 16 + (l & 15);
    B1p[i] = f2bf(w1[f * 256 + c * 16 + k]);
}
// B2p[((k*4+nf)*64 + l)*8 + j] = w2[f2][f1*16+k], f2=nf*16+(l&15), f1=(l>>4)*8+j
__global__ void pack_w2(const float* __restrict__ w2, u16* __restrict__ B2p) {
    int i = blockIdx.x * 256 + threadIdx.x;   // 32768
    int j = i & 7, l = (i >> 3) & 63, nf = (i >> 9) & 3, k = i >> 11;
    int f1 = (l >> 4) * 8 + j;
    int f2 = nf * 16 + (l & 15);
    B2p[i] = f2bf(w2[f2 * 512 + f1 * 16 + k]);
}

// ---------------- Chebyshev SpMM (bf16, XCD-swizzled, 64-col blocks) ----------------
template<int WLOG, int NRBLOG>
__global__ void spmm_cheb(const u16* __restrict__ prev, const u16* __restrict__ prev2,
                          u16* __restrict__ out,
                          const int* __restrict__ cols, const float* __restrict__ vals,
                          int nwg, float scale, int sub) {
    int bid = blockIdx.x;
    int q = nwg >> 3;
    int wid = (bid & 7) * q + (bid >> 3);      // bijective: col-block slow per XCD
    int cb = wid >> NRBLOG;
    int r4 = wid & ((1 << NRBLOG) - 1);
    int lane = threadIdx.x & 63;
    int r   = r4 * 4 + (threadIdx.x >> 6);
    int col = cb * 64 + lane;
    int   c_l = cols[r * 16 + (lane & 15)];
    float v_l = vals[r * 16 + (lane & 15)];
    float acc = 0.f;
#pragma unroll
    for (int j = 0; j < 16; j++) {
        int   cidx = __shfl(c_l, j);
        float vv   = __shfl(v_l, j);
        acc += vv * bf2f(prev[((size_t)cidx << WLOG) + col]);
    }
    float o = scale * acc;
    if (sub) o -= bf2f(prev2[((size_t)r << WLOG) + col]);
    out[((size_t)r << WLOG) + col] = f2bf(o);
}

// ------- GEMM1 (MFMA): (v,b)x(c,k) @ w1 -> relu -> pool4 over v -> XS2 slice0 -------
// grid V1/8; 4 waves: nf = w&1, vq = w>>1; BK=32 (2 k-slices)
__launch_bounds__(256)
__global__ void gemm1_mfma(const u16* __restrict__ XS1, const u16* __restrict__ B1p,
                           const float* __restrict__ b1, u16* __restrict__ XS2_0) {
    __shared__ u16 As[2][4096];     // [buf]: slice(2) x row(8) x col(256)
    int t = threadIdx.x;
    int w = t >> 6, l = t & 63;
    int v0 = blockIdx.x * 8;
    int nf = w & 1, vq = w >> 1;

    f32x4 acc[4] = {};
    {   // stage step 0 (slices 0,1)
        const short8* s0 = (const short8*)(XS1 + (size_t)(0 * V1q + v0) * 256);
        const short8* s1 = (const short8*)(XS1 + (size_t)(1 * V1q + v0) * 256);
        short8* dst = (short8*)As[0];
        dst[t] = s0[t]; dst[256 + t] = s1[t];
    }
    __syncthreads();
    for (int s = 0; s < 8; s++) {
        int cur = s & 1;
        if (s < 7) {
            const short8* s0 = (const short8*)(XS1 + (size_t)((2 * s + 2) * V1q + v0) * 256);
            const short8* s1 = (const short8*)(XS1 + (size_t)((2 * s + 3) * V1q + v0) * 256);
            short8* dst = (short8*)As[cur ^ 1];
            dst[t] = s0[t]; dst[256 + t] = s1[t];
        }
        short8 bfrag = *(const short8*)(B1p + (((size_t)s * 2 + nf) * 64 + l) * 8);
        int abase = (l >> 5) * 2048 + (l & 31) * 8;   // kk*2048 + lane-linear 512B row slice
#pragma unroll
        for (int fm = 0; fm < 4; fm++) {
            int vl = vq * 4 + fm;
            short8 afrag = *(const short8*)&As[cur][abase + vl * 256];
            acc[fm] = __builtin_amdgcn_mfma_f32_16x16x32_bf16(afrag, bfrag, acc[fm], 0, 0, 0);
        }
        __syncthreads();
    }
    // pool4 over fm (4 consecutive v) in-lane, bias+relu, scatter bf16
    f32x4 m = acc[0];
#pragma unroll
    for (int fm = 1; fm < 4; fm++) {
#pragma unroll
        for (int i = 0; i < 4; i++) m[i] = fmaxf(m[i], acc[fm][i]);
    }
    int f1 = nf * 16 + (l & 15);
    float bias = b1[f1];
    int u_out = blockIdx.x * 2 + vq;
    u16* orow = XS2_0 + (size_t)u_out * 512;
    int colbase = ((f1 >> 3) << 7) | (f1 & 7);
#pragma unroll
    for (int reg = 0; reg < 4; reg++) {
        int b = (l >> 4) * 4 + reg;
        orow[colbase + b * 8] = f2bf(fmaxf(m[reg] + bias, 0.f));
    }
}

// ------- GEMM2 (MFMA): (u,b)x(f1,k) @ w2 -> relu -> pool4 over u -> P2f fp32 -------
// grid V2/16; 4 waves: wave w = u-quad w, all 4 nf; BK=32 (1 k-slice)
__launch_bounds__(256)
__global__ void gemm2_mfma(const u16* __restrict__ XS2, const u16* __restrict__ B2p,
                           const float* __restrict__ b2, float* __restrict__ P2f) {
    __shared__ u16 As[2][8192];          // [buf]: row(16) x col(512)
    __shared__ float ylds[4 * 16 * 66];  // [w][b][f2] padded
    int t = threadIdx.x;
    int w = t >> 6, l = t & 63;
    int u0 = blockIdx.x * 16;

    f32x4 acc[4][4] = {};
    {   // stage k=0
        const short8* src = (const short8*)(XS2 + (size_t)(0 * V2q + u0) * 512);
        short8* dst = (short8*)As[0];
#pragma unroll
        for (int r = 0; r < 4; r++) dst[t * 4 + r] = src[t * 4 + r];
    }
    __syncthreads();
    for (int k = 0; k < 16; k++) {
        int cur = k & 1;
        if (k < 15) {
            const short8* src = (const short8*)(XS2 + (size_t)((k + 1) * V2q + u0) * 512);
            short8* dst = (short8*)As[cur ^ 1];
#pragma unroll
            for (int r = 0; r < 4; r++) dst[t * 4 + r] = src[t * 4 + r];
        }
        short8 bfrag[4];
#pragma unroll
        for (int nf = 0; nf < 4; nf++)
            bfrag[nf] = *(const short8*)(B2p + (((size_t)k * 4 + nf) * 64 + l) * 8);
#pragma unroll
        for (int fm = 0; fm < 4; fm++) {
            int ul = w * 4 + fm;
            short8 afrag = *(const short8*)&As[cur][ul * 512 + l * 8];
#pragma unroll
            for (int nf = 0; nf < 4; nf++)
                acc[fm][nf] = __builtin_amdgcn_mfma_f32_16x16x32_bf16(afrag, bfrag[nf], acc[fm][nf], 0, 0, 0);
        }
        __syncthreads();
    }
    // pool over fm (4 consecutive u), bias+relu, repack to LDS
#pragma unroll
    for (int nf = 0; nf < 4; nf++) {
        int f2 = nf * 16 + (l & 15);
        float bias = b2[f2];
#pragma unroll
        for (int reg = 0; reg < 4; reg++) {
            int b = (l >> 4) * 4 + reg;
            float m = fmaxf(fmaxf(acc[0][nf][reg], acc[1][nf][reg]),
                            fmaxf(acc[2][nf][reg], acc[3][nf][reg]));
            ylds[(w * 16 + b) * 66 + f2] = fmaxf(m + bias, 0.f);
        }
    }
    __syncthreads();
    int ub = blockIdx.x * 4;
#pragma unroll
    for (int i = 0; i < 4; i++) {
        int p = t + i * 256;
        int b = p >> 6, f2 = p & 63;
        float4 v;
        v.x = ylds[(0 * 16 + b) * 66 + f2];
        v.y = ylds[(1 * 16 + b) * 66 + f2];
        v.z = ylds[(2 * 16 + b) * 66 + f2];
        v.w = ylds[(3 * 16 + b) * 66 + f2];
        *(float4*)&P2f[(size_t)(b * 64 + f2) * 1024 + ub] = v;
    }
}

// ---------------- FC ----------------
__global__ void fc_init(const float* __restrict__ b, float* __restrict__ out) {
    int i = blockIdx.x * 256 + threadIdx.x;   // 8192
    out[i] = b[i & 511];
}

__launch_bounds__(256)
__global__ void fc1k(const float* __restrict__ P2f, const float* __restrict__ W,
                     float* __restrict__ out) {
    __shared__ float plds[16][260];
    __shared__ float wlds[32][260];
    int t = threadIdx.x;
    int o0 = blockIdx.x * 32;
    int cbase = blockIdx.y * 2048;
    int b = t & 15, og = t >> 4;
    float acc0 = 0.f, acc1 = 0.f;
    for (int ch = 0; ch < 8; ch++) {
        int cc = cbase + ch * 256;
        __syncthreads();
        {
            int row = t >> 4, base = (t & 15) * 16;
            const float* src = P2f + (size_t)row * FCIN + cc + base;
            for (int q = 0; q < 16; q += 4)
                *(float4*)&plds[row][base + q] = *(const float4*)(src + q);
        }
        {
            int row = t >> 3, base = (t & 7) * 32;
            const float* src = W + (size_t)(o0 + row) * FCIN + cc + base;
            for (int q = 0; q < 32; q += 4)
                *(float4*)&wlds[row][base + q] = *(const float4*)(src + q);
        }
        __syncthreads();
#pragma unroll
        for (int j = 0; j < 256; j += 4) {
            float4 a  = *(const float4*)&plds[b][j];
            float4 wa = *(const float4*)&wlds[og][j];
            float4 wb = *(const float4*)&wlds[og + 16][j];
            acc0 += a.x * wa.x + a.y * wa.y + a.z * wa.z + a.w * wa.w;
            acc1 += a.x * wb.x + a.y * wb.y + a.z * wb.z + a.w * wb.w;
        }
    }
    atomicAdd(&out[b * 512 + o0 + og], acc0);
    atomicAdd(&out[b * 512 + o0 + og + 16], acc1);
}

extern "C" void kernel_launch(void* const* d_in, const int* in_sizes, int n_in,
                              void* d_out, int out_size, void* d_ws, size_t ws_size,
                              hipStream_t stream) {
    const float* x       = (const float*)d_in[0];
    const int*   perm    = (const int*)d_in[1];
    const int*   l1_cols = (const int*)d_in[3];
    const float* l1_vals = (const float*)d_in[4];
    const int*   l2_cols = (const int*)d_in[6];
    const float* l2_vals = (const float*)d_in[7];
    const float* w1      = (const float*)d_in[8];
    const float* b1      = (const float*)d_in[9];
    const float* w2      = (const float*)d_in[10];
    const float* b2      = (const float*)d_in[11];
    const float* fcw     = (const float*)d_in[12];
    const float* fcb     = (const float*)d_in[13];
    float* out = (float*)d_out;

    char* wsb = (char*)d_ws;
    size_t off = 0;
    auto alloc = [&](size_t bytes) -> void* {
        void* p = wsb + off;
        off += (bytes + 255) & ~(size_t)255;
        return p;
    };
    float* mean_rstd = (float*)alloc(32 * 4);
    float* bnpart    = (float*)alloc(16 * 64 * 2 * 4);
    int*   iperm     = (int*)alloc((size_t)V1q * 4);
    u16*   B1p       = (u16*)alloc(8192 * 2);
    u16*   B2p       = (u16*)alloc(32768 * 2);
    u16*   XS1       = (u16*)alloc((size_t)Kq * V1q * 256 * 2);
    u16*   XS2       = (u16*)alloc((size_t)Kq * V2q * 512 * 2);
    float* P2f       = (float*)alloc((size_t)16 * FCIN * 4);
    (void)ws_size; (void)in_sizes; (void)n_in; (void)out_size;

    const size_t S1 = (size_t)V1q * 256;
    const size_t S2 = (size_t)V2q * 512;

    bn_part<<<dim3(64, 16), 256, 0, stream>>>(x, bnpart);
    bn_final<<<1, 256, 0, stream>>>(bnpart, mean_rstd);
    build_iperm<<<V1q / 256, 256, 0, stream>>>(perm, iperm);
    hipMemsetAsync(XS1, 0, S1 * 2, stream);
    norm_transpose_scatter<<<500, 256, 0, stream>>>(x, mean_rstd, iperm, XS1);
    pack_w1<<<32, 256, 0, stream>>>(w1, B1p);
    pack_w2<<<128, 256, 0, stream>>>(w2, B2p);

    // Chebyshev levels, conv1: 4 col-blocks x 4096 row-quads
    spmm_cheb<8, 12><<<16384, 256, 0, stream>>>(XS1, XS1, XS1 + S1, l1_cols, l1_vals, 16384, 1.f, 0);
    for (int k = 2; k < Kq; k++)
        spmm_cheb<8, 12><<<16384, 256, 0, stream>>>(XS1 + (size_t)(k - 1) * S1, XS1 + (size_t)(k - 2) * S1,
                                                    XS1 + (size_t)k * S1, l1_cols, l1_vals, 16384, 2.f, 1);
    gemm1_mfma<<<V1q / 8, 256, 0, stream>>>(XS1, B1p, b1, XS2);

    // Chebyshev levels, conv2: 8 col-blocks x 1024 row-quads
    spmm_cheb<9, 10><<<8192, 256, 0, stream>>>(XS2, XS2, XS2 + S2, l2_cols, l2_vals, 8192, 1.f, 0);
    for (int k = 2; k < Kq; k++)
        spmm_cheb<9, 10><<<8192, 256, 0, stream>>>(XS2 + (size_t)(k - 1) * S2, XS2 + (size_t)(k - 2) * S2,
                                                   XS2 + (size_t)k * S2, l2_cols, l2_vals, 8192, 2.f, 1);
    gemm2_mfma<<<V2q / 16, 256, 0, stream>>>(XS2, B2p, b2, P2f);

    fc_init<<<32, 256, 0, stream>>>(fcb, out);
    fc1k<<<dim3(16, 32), 256, 0, stream>>>(P2f, fcw, out);
}

// Round 3
// 506.788 us; speedup vs baseline: 1.8981x; 1.3864x over previous
//
#include <hip/hip_runtime.h>

#define VIN  16000
#define V1q  16384
#define V2q  4096
#define Kq   16
#define F1q  32
#define F2q  64
#define FCIN 65536

typedef unsigned short u16;
typedef __attribute__((ext_vector_type(8))) short short8;
typedef __attribute__((ext_vector_type(4))) float f32x4;

__device__ __forceinline__ float bf2f(u16 v) { return __uint_as_float((unsigned)v << 16); }
__device__ __forceinline__ u16 f2bf(float f) {
    unsigned u = __float_as_uint(f);
    return (u16)((u + 0x7fffu + ((u >> 16) & 1u)) >> 16);
}

// ---------------- BatchNorm stats (two stage) ----------------
__global__ void bn_part(const float* __restrict__ x, float* __restrict__ part) {
    int c  = blockIdx.y;
    int bx = blockIdx.x;           // 0..63
    int b  = bx >> 2;
    int vc = bx & 3;
    const float* p = x + (size_t)(b * 16 + c) * VIN + vc * 4000;
    float s = 0.f, s2 = 0.f;
    for (int v = threadIdx.x; v < 4000; v += 256) {
        float val = p[v];
        s += val; s2 += val * val;
    }
    for (int o = 32; o; o >>= 1) { s += __shfl_down(s, o); s2 += __shfl_down(s2, o); }
    __shared__ float ls[4], ls2[4];
    int wid = threadIdx.x >> 6;
    if ((threadIdx.x & 63) == 0) { ls[wid] = s; ls2[wid] = s2; }
    __syncthreads();
    if (threadIdx.x == 0) {
        s = ls[0] + ls[1] + ls[2] + ls[3];
        s2 = ls2[0] + ls2[1] + ls2[2] + ls2[3];
        part[(c * 64 + bx) * 2]     = s;
        part[(c * 64 + bx) * 2 + 1] = s2;
    }
}

__global__ void bn_final(const float* __restrict__ part, float* __restrict__ mean_rstd) {
    int t = threadIdx.x;
    int c = t >> 4, j = t & 15;
    float s = 0.f, s2 = 0.f;
    for (int i = 0; i < 4; i++) {
        s  += part[(c * 64 + j * 4 + i) * 2];
        s2 += part[(c * 64 + j * 4 + i) * 2 + 1];
    }
    for (int o = 8; o; o >>= 1) { s += __shfl_down(s, o, 16); s2 += __shfl_down(s2, o, 16); }
    if (j == 0) {
        float m  = s / 256000.f;
        float var = s2 / 256000.f - m * m;
        mean_rstd[c]      = m;
        mean_rstd[16 + c] = rsqrtf(var + 1e-5f);
    }
}

// ---------------- inverse permutation ----------------
__global__ void build_iperm(const int* __restrict__ perm, int* __restrict__ iperm) {
    int v = blockIdx.x * 256 + threadIdx.x;
    if (v < V1q) iperm[perm[v]] = v;
}

// ------- normalize + transpose + permute scatter, bf16, fragment column order -------
// X0 row v (256 cols): value (b,c) stored at col' = (c>>3)*128 + b*8 + (c&7)
__global__ void norm_transpose_scatter(const float* __restrict__ x,
                                       const float* __restrict__ mean_rstd,
                                       const int* __restrict__ iperm,
                                       u16* __restrict__ X0) {
    __shared__ u16 tile[256][33];
    int u0 = blockIdx.x * 32;
    int t  = threadIdx.x;
    int jj = t & 31, half = t >> 5;
    for (int rr = 0; rr < 32; rr++) {
        int s = rr * 8 + half;           // source row = b*16 + c
        int c = s & 15, b = s >> 4;
        float val = x[(size_t)s * VIN + u0 + jj];
        val = (val - mean_rstd[c]) * mean_rstd[16 + c];
        int d = ((c >> 3) << 7) | (b << 3) | (c & 7);
        tile[d][jj] = f2bf(val);
    }
    __syncthreads();
    for (int j = 0; j < 32; j++) {
        int tv = iperm[u0 + j];
        X0[(size_t)tv * 256 + t] = tile[t][j];
    }
}

// ---------------- weight packing into MFMA B-fragment order ----------------
__global__ void pack_w1(const float* __restrict__ w1, u16* __restrict__ B1p) {
    int i = blockIdx.x * 256 + threadIdx.x;   // 8192
    int j = i & 7, l = (i >> 3) & 63, nf = (i >> 9) & 1, s = i >> 10;
    int q = l >> 4;
    int k = s * 2 + (q >> 1);
    int c = (q & 1) * 8 + j;
    int f = nf * 16 + (l & 15);
    B1p[i] = f2bf(w1[f * 256 + c * 16 + k]);
}
__global__ void pack_w2(const float* __restrict__ w2, u16* __restrict__ B2p) {
    int i = blockIdx.x * 256 + threadIdx.x;   // 32768
    int j = i & 7, l = (i >> 3) & 63, nf = (i >> 9) & 3, k = i >> 11;
    int f1 = (l >> 4) * 8 + j;
    int f2 = nf * 16 + (l & 15);
    B2p[i] = f2bf(w2[f2 * 512 + f1 * 16 + k]);
}

// ---------------- Chebyshev SpMM (bf16, scalar-uniform row data, XCD-swizzled) ----------------
template<int WLOG, int NRBLOG>
__global__ void spmm_cheb(const u16* __restrict__ prev, const u16* __restrict__ prev2,
                          u16* __restrict__ out,
                          const int* __restrict__ cols, const float* __restrict__ vals,
                          int nwg, float scale, int sub) {
    int bid = blockIdx.x;
    int q = nwg >> 3;
    int wid = (bid & 7) * q + (bid >> 3);      // bijective: col-block slow per XCD
    int cb = wid >> NRBLOG;
    int r4 = wid & ((1 << NRBLOG) - 1);
    int lane = threadIdx.x & 63;
    int r = __builtin_amdgcn_readfirstlane(r4 * 4 + (threadIdx.x >> 6));  // wave-uniform row
    int col = (cb << 6) + lane;
    const int4*   cp = (const int4*)(cols + r * 16);
    const float4* vp = (const float4*)(vals + r * 16);
    float acc = 0.f;
#pragma unroll
    for (int ii = 0; ii < 4; ii++) {
        int4   ci = cp[ii];
        float4 vi = vp[ii];
        const u16* p0 = prev + ((size_t)__builtin_amdgcn_readfirstlane(ci.x) << WLOG);
        const u16* p1 = prev + ((size_t)__builtin_amdgcn_readfirstlane(ci.y) << WLOG);
        const u16* p2 = prev + ((size_t)__builtin_amdgcn_readfirstlane(ci.z) << WLOG);
        const u16* p3 = prev + ((size_t)__builtin_amdgcn_readfirstlane(ci.w) << WLOG);
        acc += vi.x * bf2f(p0[col]);
        acc += vi.y * bf2f(p1[col]);
        acc += vi.z * bf2f(p2[col]);
        acc += vi.w * bf2f(p3[col]);
    }
    float o = scale * acc;
    if (sub) o -= bf2f(prev2[((size_t)r << WLOG) + col]);
    out[((size_t)r << WLOG) + col] = f2bf(o);
}

// ------- GEMM1 (MFMA): (v,b)x(c,k) @ w1 -> relu -> pool4 over v -> XS2 slice0 -------
__launch_bounds__(256)
__global__ void gemm1_mfma(const u16* __restrict__ XS1, const u16* __restrict__ B1p,
                           const float* __restrict__ b1, u16* __restrict__ XS2_0) {
    __shared__ u16 As[2][4096];     // [buf]: slice(2) x row(8) x col(256)
    int t = threadIdx.x;
    int w = t >> 6, l = t & 63;
    int v0 = blockIdx.x * 8;
    int nf = w & 1, vq = w >> 1;

    f32x4 acc[4] = {};
    {
        const short8* s0 = (const short8*)(XS1 + (size_t)(0 * V1q + v0) * 256);
        const short8* s1 = (const short8*)(XS1 + (size_t)(1 * V1q + v0) * 256);
        short8* dst = (short8*)As[0];
        dst[t] = s0[t]; dst[256 + t] = s1[t];
    }
    __syncthreads();
    for (int s = 0; s < 8; s++) {
        int cur = s & 1;
        if (s < 7) {
            const short8* s0 = (const short8*)(XS1 + (size_t)((2 * s + 2) * V1q + v0) * 256);
            const short8* s1 = (const short8*)(XS1 + (size_t)((2 * s + 3) * V1q + v0) * 256);
            short8* dst = (short8*)As[cur ^ 1];
            dst[t] = s0[t]; dst[256 + t] = s1[t];
        }
        short8 bfrag = *(const short8*)(B1p + (((size_t)s * 2 + nf) * 64 + l) * 8);
        int abase = (l >> 5) * 2048 + (l & 31) * 8;
#pragma unroll
        for (int fm = 0; fm < 4; fm++) {
            int vl = vq * 4 + fm;
            short8 afrag = *(const short8*)&As[cur][abase + vl * 256];
            acc[fm] = __builtin_amdgcn_mfma_f32_16x16x32_bf16(afrag, bfrag, acc[fm], 0, 0, 0);
        }
        __syncthreads();
    }
    f32x4 m = acc[0];
#pragma unroll
    for (int fm = 1; fm < 4; fm++) {
#pragma unroll
        for (int i = 0; i < 4; i++) m[i] = fmaxf(m[i], acc[fm][i]);
    }
    int f1 = nf * 16 + (l & 15);
    float bias = b1[f1];
    int u_out = blockIdx.x * 2 + vq;
    u16* orow = XS2_0 + (size_t)u_out * 512;
    int colbase = ((f1 >> 3) << 7) | (f1 & 7);
#pragma unroll
    for (int reg = 0; reg < 4; reg++) {
        int b = (l >> 4) * 4 + reg;
        orow[colbase + b * 8] = f2bf(fmaxf(m[reg] + bias, 0.f));
    }
}

// ------- GEMM2 (MFMA): (u,b)x(f1,k) @ w2 -> relu -> pool4 over u -> P2f fp32 -------
__launch_bounds__(256)
__global__ void gemm2_mfma(const u16* __restrict__ XS2, const u16* __restrict__ B2p,
                           const float* __restrict__ b2, float* __restrict__ P2f) {
    __shared__ u16 As[2][8192];          // [buf]: row(16) x col(512)
    __shared__ float ylds[4 * 16 * 66];  // [w][b][f2] padded
    int t = threadIdx.x;
    int w = t >> 6, l = t & 63;
    int u0 = blockIdx.x * 16;

    f32x4 acc[4][4] = {};
    {
        const short8* src = (const short8*)(XS2 + (size_t)(0 * V2q + u0) * 512);
        short8* dst = (short8*)As[0];
#pragma unroll
        for (int r = 0; r < 4; r++) dst[t * 4 + r] = src[t * 4 + r];
    }
    __syncthreads();
    for (int k = 0; k < 16; k++) {
        int cur = k & 1;
        if (k < 15) {
            const short8* src = (const short8*)(XS2 + (size_t)((k + 1) * V2q + u0) * 512);
            short8* dst = (short8*)As[cur ^ 1];
#pragma unroll
            for (int r = 0; r < 4; r++) dst[t * 4 + r] = src[t * 4 + r];
        }
        short8 bfrag[4];
#pragma unroll
        for (int nf = 0; nf < 4; nf++)
            bfrag[nf] = *(const short8*)(B2p + (((size_t)k * 4 + nf) * 64 + l) * 8);
#pragma unroll
        for (int fm = 0; fm < 4; fm++) {
            int ul = w * 4 + fm;
            short8 afrag = *(const short8*)&As[cur][ul * 512 + l * 8];
#pragma unroll
            for (int nf = 0; nf < 4; nf++)
                acc[fm][nf] = __builtin_amdgcn_mfma_f32_16x16x32_bf16(afrag, bfrag[nf], acc[fm][nf], 0, 0, 0);
        }
        __syncthreads();
    }
#pragma unroll
    for (int nf = 0; nf < 4; nf++) {
        int f2 = nf * 16 + (l & 15);
        float bias = b2[f2];
#pragma unroll
        for (int reg = 0; reg < 4; reg++) {
            int b = (l >> 4) * 4 + reg;
            float m = fmaxf(fmaxf(acc[0][nf][reg], acc[1][nf][reg]),
                            fmaxf(acc[2][nf][reg], acc[3][nf][reg]));
            ylds[(w * 16 + b) * 66 + f2] = fmaxf(m + bias, 0.f);
        }
    }
    __syncthreads();
    int ub = blockIdx.x * 4;
#pragma unroll
    for (int i = 0; i < 4; i++) {
        int p = t + i * 256;
        int b = p >> 6, f2 = p & 63;
        float4 v;
        v.x = ylds[(0 * 16 + b) * 66 + f2];
        v.y = ylds[(1 * 16 + b) * 66 + f2];
        v.z = ylds[(2 * 16 + b) * 66 + f2];
        v.w = ylds[(3 * 16 + b) * 66 + f2];
        *(float4*)&P2f[(size_t)(b * 64 + f2) * 1024 + ub] = v;
    }
}

// ---------------- FC ----------------
__global__ void fc_init(const float* __restrict__ b, float* __restrict__ out) {
    int i = blockIdx.x * 256 + threadIdx.x;   // 8192
    out[i] = b[i & 511];
}

// streaming FC: grid (64 o-groups of 8, 16 k-chunks of 4096); 4 waves x 2 outputs
__launch_bounds__(256)
__global__ void fc1k(const float* __restrict__ P2f, const float* __restrict__ W,
                     float* __restrict__ out) {
    __shared__ float red[4][64][17];
    int t = threadIdx.x;
    int w = t >> 6, l = t & 63;
    int o0 = blockIdx.x * 8 + w * 2;
    int k0 = blockIdx.y * 4096;
    const float* wr0 = W + (size_t)o0 * FCIN + k0;
    const float* wr1 = W + (size_t)(o0 + 1) * FCIN + k0;
    const float* pb  = P2f + k0;
    float acc0[16], acc1[16];
#pragma unroll
    for (int b = 0; b < 16; b++) { acc0[b] = 0.f; acc1[b] = 0.f; }
    for (int it = 0; it < 16; it++) {
        int kk = it * 256 + l * 4;
        float4 wa = *(const float4*)(wr0 + kk);
        float4 wb = *(const float4*)(wr1 + kk);
#pragma unroll
        for (int b = 0; b < 16; b++) {
            float4 p = *(const float4*)(pb + (size_t)b * FCIN + kk);
            acc0[b] += wa.x * p.x + wa.y * p.y + wa.z * p.z + wa.w * p.w;
            acc1[b] += wb.x * p.x + wb.y * p.y + wb.z * p.z + wb.w * p.w;
        }
    }
    int qq = l >> 4, bb = l & 15;
    // reduce acc0
    __syncthreads();
#pragma unroll
    for (int b = 0; b < 16; b++) red[w][l][b] = acc0[b];
    __syncthreads();
    {
        float s = 0.f;
#pragma unroll
        for (int i = 0; i < 16; i++) s += red[w][qq * 16 + i][bb];
        s += __shfl_down(s, 16);
        s += __shfl_down(s, 32);
        if (l < 16) atomicAdd(&out[bb * 512 + o0], s);
    }
    // reduce acc1
    __syncthreads();
#pragma unroll
    for (int b = 0; b < 16; b++) red[w][l][b] = acc1[b];
    __syncthreads();
    {
        float s = 0.f;
#pragma unroll
        for (int i = 0; i < 16; i++) s += red[w][qq * 16 + i][bb];
        s += __shfl_down(s, 16);
        s += __shfl_down(s, 32);
        if (l < 16) atomicAdd(&out[bb * 512 + o0 + 1], s);
    }
}

extern "C" void kernel_launch(void* const* d_in, const int* in_sizes, int n_in,
                              void* d_out, int out_size, void* d_ws, size_t ws_size,
                              hipStream_t stream) {
    const float* x       = (const float*)d_in[0];
    const int*   perm    = (const int*)d_in[1];
    const int*   l1_cols = (const int*)d_in[3];
    const float* l1_vals = (const float*)d_in[4];
    const int*   l2_cols = (const int*)d_in[6];
    const float* l2_vals = (const float*)d_in[7];
    const float* w1      = (const float*)d_in[8];
    const float* b1      = (const float*)d_in[9];
    const float* w2      = (const float*)d_in[10];
    const float* b2      = (const float*)d_in[11];
    const float* fcw     = (const float*)d_in[12];
    const float* fcb     = (const float*)d_in[13];
    float* out = (float*)d_out;

    char* wsb = (char*)d_ws;
    size_t off = 0;
    auto alloc = [&](size_t bytes) -> void* {
        void* p = wsb + off;
        off += (bytes + 255) & ~(size_t)255;
        return p;
    };
    float* mean_rstd = (float*)alloc(32 * 4);
    float* bnpart    = (float*)alloc(16 * 64 * 2 * 4);
    int*   iperm     = (int*)alloc((size_t)V1q * 4);
    u16*   B1p       = (u16*)alloc(8192 * 2);
    u16*   B2p       = (u16*)alloc(32768 * 2);
    u16*   XS1       = (u16*)alloc((size_t)Kq * V1q * 256 * 2);
    u16*   XS2       = (u16*)alloc((size_t)Kq * V2q * 512 * 2);
    float* P2f       = (float*)alloc((size_t)16 * FCIN * 4);
    (void)ws_size; (void)in_sizes; (void)n_in; (void)out_size;

    const size_t S1 = (size_t)V1q * 256;
    const size_t S2 = (size_t)V2q * 512;

    bn_part<<<dim3(64, 16), 256, 0, stream>>>(x, bnpart);
    bn_final<<<1, 256, 0, stream>>>(bnpart, mean_rstd);
    build_iperm<<<V1q / 256, 256, 0, stream>>>(perm, iperm);
    hipMemsetAsync(XS1, 0, S1 * 2, stream);
    norm_transpose_scatter<<<500, 256, 0, stream>>>(x, mean_rstd, iperm, XS1);
    pack_w1<<<32, 256, 0, stream>>>(w1, B1p);
    pack_w2<<<128, 256, 0, stream>>>(w2, B2p);

    // Chebyshev levels, conv1: 4 col-blocks x 4096 row-quads
    spmm_cheb<8, 12><<<16384, 256, 0, stream>>>(XS1, XS1, XS1 + S1, l1_cols, l1_vals, 16384, 1.f, 0);
    for (int k = 2; k < Kq; k++)
        spmm_cheb<8, 12><<<16384, 256, 0, stream>>>(XS1 + (size_t)(k - 1) * S1, XS1 + (size_t)(k - 2) * S1,
                                                    XS1 + (size_t)k * S1, l1_cols, l1_vals, 16384, 2.f, 1);
    gemm1_mfma<<<V1q / 8, 256, 0, stream>>>(XS1, B1p, b1, XS2);

    // Chebyshev levels, conv2: 8 col-blocks x 1024 row-quads
    spmm_cheb<9, 10><<<8192, 256, 0, stream>>>(XS2, XS2, XS2 + S2, l2_cols, l2_vals, 8192, 1.f, 0);
    for (int k = 2; k < Kq; k++)
        spmm_cheb<9, 10><<<8192, 256, 0, stream>>>(XS2 + (size_t)(k - 1) * S2, XS2 + (size_t)(k - 2) * S2,
                                                   XS2 + (size_t)k * S2, l2_cols, l2_vals, 8192, 2.f, 1);
    gemm2_mfma<<<V2q / 16, 256, 0, stream>>>(XS2, B2p, b2, P2f);

    fc_init<<<32, 256, 0, stream>>>(fcb, out);
    fc1k<<<dim3(64, 16), 256, 0, stream>>>(P2f, fcw, out);
}

// Round 4
// 481.026 us; speedup vs baseline: 1.9997x; 1.0536x over previous
//
#include <hip/hip_runtime.h>

#define VIN  16000
#define V1q  16384
#define V2q  4096
#define Kq   16
#define F1q  32
#define F2q  64
#define FCIN 65536

typedef unsigned short u16;
typedef __attribute__((ext_vector_type(8))) short short8;
typedef __attribute__((ext_vector_type(4))) float f32x4;

__device__ __forceinline__ float bf2f(u16 v) { return __uint_as_float((unsigned)v << 16); }
__device__ __forceinline__ u16 f2bf(float f) {
    unsigned u = __float_as_uint(f);
    return (u16)((u + 0x7fffu + ((u >> 16) & 1u)) >> 16);
}

// ---------------- BatchNorm stats (two stage) ----------------
__global__ void bn_part(const float* __restrict__ x, float* __restrict__ part) {
    int c  = blockIdx.y;
    int bx = blockIdx.x;           // 0..63
    int b  = bx >> 2;
    int vc = bx & 3;
    const float* p = x + (size_t)(b * 16 + c) * VIN + vc * 4000;
    float s = 0.f, s2 = 0.f;
    for (int v = threadIdx.x; v < 4000; v += 256) {
        float val = p[v];
        s += val; s2 += val * val;
    }
    for (int o = 32; o; o >>= 1) { s += __shfl_down(s, o); s2 += __shfl_down(s2, o); }
    __shared__ float ls[4], ls2[4];
    int wid = threadIdx.x >> 6;
    if ((threadIdx.x & 63) == 0) { ls[wid] = s; ls2[wid] = s2; }
    __syncthreads();
    if (threadIdx.x == 0) {
        s = ls[0] + ls[1] + ls[2] + ls[3];
        s2 = ls2[0] + ls2[1] + ls2[2] + ls2[3];
        part[(c * 64 + bx) * 2]     = s;
        part[(c * 64 + bx) * 2 + 1] = s2;
    }
}

__global__ void bn_final(const float* __restrict__ part, float* __restrict__ mean_rstd) {
    int t = threadIdx.x;
    int c = t >> 4, j = t & 15;
    float s = 0.f, s2 = 0.f;
    for (int i = 0; i < 4; i++) {
        s  += part[(c * 64 + j * 4 + i) * 2];
        s2 += part[(c * 64 + j * 4 + i) * 2 + 1];
    }
    for (int o = 8; o; o >>= 1) { s += __shfl_down(s, o, 16); s2 += __shfl_down(s2, o, 16); }
    if (j == 0) {
        float m  = s / 256000.f;
        float var = s2 / 256000.f - m * m;
        mean_rstd[c]      = m;
        mean_rstd[16 + c] = rsqrtf(var + 1e-5f);
    }
}

// ---------------- inverse permutation ----------------
__global__ void build_iperm(const int* __restrict__ perm, int* __restrict__ iperm) {
    int v = blockIdx.x * 256 + threadIdx.x;
    if (v < V1q) iperm[perm[v]] = v;
}

// ------- normalize + transpose + permute scatter, bf16, fragment column order -------
__global__ void norm_transpose_scatter(const float* __restrict__ x,
                                       const float* __restrict__ mean_rstd,
                                       const int* __restrict__ iperm,
                                       u16* __restrict__ X0) {
    __shared__ u16 tile[256][33];
    int u0 = blockIdx.x * 32;
    int t  = threadIdx.x;
    int jj = t & 31, half = t >> 5;
    for (int rr = 0; rr < 32; rr++) {
        int s = rr * 8 + half;           // source row = b*16 + c
        int c = s & 15, b = s >> 4;
        float val = x[(size_t)s * VIN + u0 + jj];
        val = (val - mean_rstd[c]) * mean_rstd[16 + c];
        int d = ((c >> 3) << 7) | (b << 3) | (c & 7);
        tile[d][jj] = f2bf(val);
    }
    __syncthreads();
    for (int j = 0; j < 32; j++) {
        int tv = iperm[u0 + j];
        X0[(size_t)tv * 256 + t] = tile[t][j];
    }
}

// ---------------- weight packing into MFMA B-fragment order ----------------
__global__ void pack_w1(const float* __restrict__ w1, u16* __restrict__ B1p) {
    int i = blockIdx.x * 256 + threadIdx.x;   // 8192
    int j = i & 7, l = (i >> 3) & 63, nf = (i >> 9) & 1, s = i >> 10;
    int q = l >> 4;
    int k = s * 2 + (q >> 1);
    int c = (q & 1) * 8 + j;
    int f = nf * 16 + (l & 15);
    B1p[i] = f2bf(w1[f * 256 + c * 16 + k]);
}
__global__ void pack_w2(const float* __restrict__ w2, u16* __restrict__ B2p) {
    int i = blockIdx.x * 256 + threadIdx.x;   // 32768
    int j = i & 7, l = (i >> 3) & 63, nf = (i >> 9) & 3, k = i >> 11;
    int f1 = (l >> 4) * 8 + j;
    int f2 = nf * 16 + (l & 15);
    B2p[i] = f2bf(w2[f2 * 512 + f1 * 16 + k]);
}

// ------- pack P2f fp32 -> bf16 A-fragment order for FC MFMA -------
// Pp[(ks*64 + l)*8 + j] = bf16(P2f[b=l&15][ks*32 + (l>>4)*8 + j]), ks=0..2047
__global__ void pack_p(const float* __restrict__ P2f, u16* __restrict__ Pp) {
    int i = blockIdx.x * 256 + threadIdx.x;   // 131072
    int l = i & 63, ks = i >> 6;
    int b = l & 15, q = l >> 4;
    const float* src = P2f + (size_t)b * FCIN + ks * 32 + q * 8;
    float4 a0 = *(const float4*)(src);
    float4 a1 = *(const float4*)(src + 4);
    short8 v;
    v[0] = (short)f2bf(a0.x); v[1] = (short)f2bf(a0.y);
    v[2] = (short)f2bf(a0.z); v[3] = (short)f2bf(a0.w);
    v[4] = (short)f2bf(a1.x); v[5] = (short)f2bf(a1.y);
    v[6] = (short)f2bf(a1.z); v[7] = (short)f2bf(a1.w);
    *(short8*)(Pp + (size_t)i * 8) = v;
}

// ---------------- Chebyshev SpMM (bf16, scalar row data, XCD-swizzled, nt writes) ----------------
template<int WLOG, int NRBLOG>
__global__ void spmm_cheb(const u16* __restrict__ prev, const u16* __restrict__ prev2,
                          u16* __restrict__ out,
                          const int* __restrict__ cols, const float* __restrict__ vals,
                          int nwg, float scale, int sub) {
    int bid = blockIdx.x;
    int q = nwg >> 3;
    int wid = (bid & 7) * q + (bid >> 3);      // bijective: col-block slow per XCD
    int cb = wid >> NRBLOG;
    int r4 = wid & ((1 << NRBLOG) - 1);
    int lane = threadIdx.x & 63;
    int r = __builtin_amdgcn_readfirstlane(r4 * 4 + (threadIdx.x >> 6));  // wave-uniform row
    int col = (cb << 6) + lane;
    const int4*   cp = (const int4*)(cols + r * 16);
    const float4* vp = (const float4*)(vals + r * 16);
    float acc = 0.f;
#pragma unroll
    for (int ii = 0; ii < 4; ii++) {
        int4   ci = cp[ii];
        float4 vi = vp[ii];
        const u16* p0 = prev + ((size_t)__builtin_amdgcn_readfirstlane(ci.x) << WLOG);
        const u16* p1 = prev + ((size_t)__builtin_amdgcn_readfirstlane(ci.y) << WLOG);
        const u16* p2 = prev + ((size_t)__builtin_amdgcn_readfirstlane(ci.z) << WLOG);
        const u16* p3 = prev + ((size_t)__builtin_amdgcn_readfirstlane(ci.w) << WLOG);
        acc += vi.x * bf2f(p0[col]);
        acc += vi.y * bf2f(p1[col]);
        acc += vi.z * bf2f(p2[col]);
        acc += vi.w * bf2f(p3[col]);
    }
    float o = scale * acc;
    if (sub) o -= bf2f(__builtin_nontemporal_load(prev2 + ((size_t)r << WLOG) + col));
    __builtin_nontemporal_store(f2bf(o), out + ((size_t)r << WLOG) + col);
}

// ------- GEMM1 (MFMA): (v,b)x(c,k) @ w1 -> relu -> pool4 over v -> XS2 slice0 -------
__launch_bounds__(256)
__global__ void gemm1_mfma(const u16* __restrict__ XS1, const u16* __restrict__ B1p,
                           const float* __restrict__ b1, u16* __restrict__ XS2_0) {
    __shared__ u16 As[2][4096];     // [buf]: slice(2) x row(8) x col(256)
    int t = threadIdx.x;
    int w = t >> 6, l = t & 63;
    int v0 = blockIdx.x * 8;
    int nf = w & 1, vq = w >> 1;

    f32x4 acc[4] = {};
    {
        const short8* s0 = (const short8*)(XS1 + (size_t)(0 * V1q + v0) * 256);
        const short8* s1 = (const short8*)(XS1 + (size_t)(1 * V1q + v0) * 256);
        short8* dst = (short8*)As[0];
        dst[t] = s0[t]; dst[256 + t] = s1[t];
    }
    __syncthreads();
    for (int s = 0; s < 8; s++) {
        int cur = s & 1;
        if (s < 7) {
            const short8* s0 = (const short8*)(XS1 + (size_t)((2 * s + 2) * V1q + v0) * 256);
            const short8* s1 = (const short8*)(XS1 + (size_t)((2 * s + 3) * V1q + v0) * 256);
            short8* dst = (short8*)As[cur ^ 1];
            dst[t] = s0[t]; dst[256 + t] = s1[t];
        }
        short8 bfrag = *(const short8*)(B1p + (((size_t)s * 2 + nf) * 64 + l) * 8);
        int abase = (l >> 5) * 2048 + (l & 31) * 8;
#pragma unroll
        for (int fm = 0; fm < 4; fm++) {
            int vl = vq * 4 + fm;
            short8 afrag = *(const short8*)&As[cur][abase + vl * 256];
            acc[fm] = __builtin_amdgcn_mfma_f32_16x16x32_bf16(afrag, bfrag, acc[fm], 0, 0, 0);
        }
        __syncthreads();
    }
    f32x4 m = acc[0];
#pragma unroll
    for (int fm = 1; fm < 4; fm++) {
#pragma unroll
        for (int i = 0; i < 4; i++) m[i] = fmaxf(m[i], acc[fm][i]);
    }
    int f1 = nf * 16 + (l & 15);
    float bias = b1[f1];
    int u_out = blockIdx.x * 2 + vq;
    u16* orow = XS2_0 + (size_t)u_out * 512;
    int colbase = ((f1 >> 3) << 7) | (f1 & 7);
#pragma unroll
    for (int reg = 0; reg < 4; reg++) {
        int b = (l >> 4) * 4 + reg;
        orow[colbase + b * 8] = f2bf(fmaxf(m[reg] + bias, 0.f));
    }
}

// ------- GEMM2 (MFMA): (u,b)x(f1,k) @ w2 -> relu -> pool4 over u -> P2f fp32 -------
__launch_bounds__(256)
__global__ void gemm2_mfma(const u16* __restrict__ XS2, const u16* __restrict__ B2p,
                           const float* __restrict__ b2, float* __restrict__ P2f) {
    __shared__ u16 As[2][8192];          // [buf]: row(16) x col(512)
    __shared__ float ylds[4 * 16 * 66];  // [w][b][f2] padded
    int t = threadIdx.x;
    int w = t >> 6, l = t & 63;
    int u0 = blockIdx.x * 16;

    f32x4 acc[4][4] = {};
    {
        const short8* src = (const short8*)(XS2 + (size_t)(0 * V2q + u0) * 512);
        short8* dst = (short8*)As[0];
#pragma unroll
        for (int r = 0; r < 4; r++) dst[t * 4 + r] = src[t * 4 + r];
    }
    __syncthreads();
    for (int k = 0; k < 16; k++) {
        int cur = k & 1;
        if (k < 15) {
            const short8* src = (const short8*)(XS2 + (size_t)((k + 1) * V2q + u0) * 512);
            short8* dst = (short8*)As[cur ^ 1];
#pragma unroll
            for (int r = 0; r < 4; r++) dst[t * 4 + r] = src[t * 4 + r];
        }
        short8 bfrag[4];
#pragma unroll
        for (int nf = 0; nf < 4; nf++)
            bfrag[nf] = *(const short8*)(B2p + (((size_t)k * 4 + nf) * 64 + l) * 8);
#pragma unroll
        for (int fm = 0; fm < 4; fm++) {
            int ul = w * 4 + fm;
            short8 afrag = *(const short8*)&As[cur][ul * 512 + l * 8];
#pragma unroll
            for (int nf = 0; nf < 4; nf++)
                acc[fm][nf] = __builtin_amdgcn_mfma_f32_16x16x32_bf16(afrag, bfrag[nf], acc[fm][nf], 0, 0, 0);
        }
        __syncthreads();
    }
#pragma unroll
    for (int nf = 0; nf < 4; nf++) {
        int f2 = nf * 16 + (l & 15);
        float bias = b2[f2];
#pragma unroll
        for (int reg = 0; reg < 4; reg++) {
            int b = (l >> 4) * 4 + reg;
            float m = fmaxf(fmaxf(acc[0][nf][reg], acc[1][nf][reg]),
                            fmaxf(acc[2][nf][reg], acc[3][nf][reg]));
            ylds[(w * 16 + b) * 66 + f2] = fmaxf(m + bias, 0.f);
        }
    }
    __syncthreads();
    int ub = blockIdx.x * 4;
#pragma unroll
    for (int i = 0; i < 4; i++) {
        int p = t + i * 256;
        int b = p >> 6, f2 = p & 63;
        float4 v;
        v.x = ylds[(0 * 16 + b) * 66 + f2];
        v.y = ylds[(1 * 16 + b) * 66 + f2];
        v.z = ylds[(2 * 16 + b) * 66 + f2];
        v.w = ylds[(3 * 16 + b) * 66 + f2];
        *(float4*)&P2f[(size_t)(b * 64 + f2) * 1024 + ub] = v;
    }
}

// ---------------- FC ----------------
__global__ void fc_init(const float* __restrict__ b, float* __restrict__ out) {
    int i = blockIdx.x * 256 + threadIdx.x;   // 8192
    out[i] = b[i & 511];
}

// FC via MFMA: M=16 batch, N=512 out, K=65536. grid (32 o-groups, 32 k-chunks of 2048).
// Wave w covers 16 k-steps of 32. W fp32 streamed + converted in-register.
__launch_bounds__(256)
__global__ void fc_mfma(const u16* __restrict__ Pp, const float* __restrict__ W,
                        float* __restrict__ out) {
    int t = threadIdx.x;
    int w = t >> 6, l = t & 63;
    int n0 = blockIdx.x * 16;
    int ks0 = blockIdx.y * 64 + w * 16;
    int o = n0 + (l & 15);
    const float* wp = W + (size_t)o * FCIN + (size_t)ks0 * 32 + (l >> 4) * 8;
    const u16*   ap = Pp + ((size_t)ks0 * 64 + l) * 8;
    f32x4 acc = {};
    for (int s = 0; s < 16; s++) {
        short8 afrag = *(const short8*)(ap + (size_t)s * 512);
        float4 w0 = *(const float4*)(wp + s * 32);
        float4 w1 = *(const float4*)(wp + s * 32 + 4);
        short8 bfrag;
        bfrag[0] = (short)f2bf(w0.x); bfrag[1] = (short)f2bf(w0.y);
        bfrag[2] = (short)f2bf(w0.z); bfrag[3] = (short)f2bf(w0.w);
        bfrag[4] = (short)f2bf(w1.x); bfrag[5] = (short)f2bf(w1.y);
        bfrag[6] = (short)f2bf(w1.z); bfrag[7] = (short)f2bf(w1.w);
        acc = __builtin_amdgcn_mfma_f32_16x16x32_bf16(afrag, bfrag, acc, 0, 0, 0);
    }
    __shared__ float red[4][256];
#pragma unroll
    for (int r = 0; r < 4; r++)
        red[w][((l >> 4) * 4 + r) * 16 + (l & 15)] = acc[r];
    __syncthreads();
    float s = red[0][t] + red[1][t] + red[2][t] + red[3][t];
    atomicAdd(&out[(t >> 4) * 512 + n0 + (t & 15)], s);
}

extern "C" void kernel_launch(void* const* d_in, const int* in_sizes, int n_in,
                              void* d_out, int out_size, void* d_ws, size_t ws_size,
                              hipStream_t stream) {
    const float* x       = (const float*)d_in[0];
    const int*   perm    = (const int*)d_in[1];
    const int*   l1_cols = (const int*)d_in[3];
    const float* l1_vals = (const float*)d_in[4];
    const int*   l2_cols = (const int*)d_in[6];
    const float* l2_vals = (const float*)d_in[7];
    const float* w1      = (const float*)d_in[8];
    const float* b1      = (const float*)d_in[9];
    const float* w2      = (const float*)d_in[10];
    const float* b2      = (const float*)d_in[11];
    const float* fcw     = (const float*)d_in[12];
    const float* fcb     = (const float*)d_in[13];
    float* out = (float*)d_out;

    char* wsb = (char*)d_ws;
    size_t off = 0;
    auto alloc = [&](size_t bytes) -> void* {
        void* p = wsb + off;
        off += (bytes + 255) & ~(size_t)255;
        return p;
    };
    float* mean_rstd = (float*)alloc(32 * 4);
    float* bnpart    = (float*)alloc(16 * 64 * 2 * 4);
    int*   iperm     = (int*)alloc((size_t)V1q * 4);
    u16*   B1p       = (u16*)alloc(8192 * 2);
    u16*   B2p       = (u16*)alloc(32768 * 2);
    u16*   XS1       = (u16*)alloc((size_t)Kq * V1q * 256 * 2);
    u16*   XS2       = (u16*)alloc((size_t)Kq * V2q * 512 * 2);
    float* P2f       = (float*)alloc((size_t)16 * FCIN * 4);
    u16*   Pp        = (u16*)alloc((size_t)16 * FCIN * 2);
    (void)ws_size; (void)in_sizes; (void)n_in; (void)out_size;

    const size_t S1 = (size_t)V1q * 256;
    const size_t S2 = (size_t)V2q * 512;

    bn_part<<<dim3(64, 16), 256, 0, stream>>>(x, bnpart);
    bn_final<<<1, 256, 0, stream>>>(bnpart, mean_rstd);
    build_iperm<<<V1q / 256, 256, 0, stream>>>(perm, iperm);
    hipMemsetAsync(XS1, 0, S1 * 2, stream);
    norm_transpose_scatter<<<500, 256, 0, stream>>>(x, mean_rstd, iperm, XS1);
    pack_w1<<<32, 256, 0, stream>>>(w1, B1p);
    pack_w2<<<128, 256, 0, stream>>>(w2, B2p);

    // Chebyshev levels, conv1: 4 col-blocks x 4096 row-quads
    spmm_cheb<8, 12><<<16384, 256, 0, stream>>>(XS1, XS1, XS1 + S1, l1_cols, l1_vals, 16384, 1.f, 0);
    for (int k = 2; k < Kq; k++)
        spmm_cheb<8, 12><<<16384, 256, 0, stream>>>(XS1 + (size_t)(k - 1) * S1, XS1 + (size_t)(k - 2) * S1,
                                                    XS1 + (size_t)k * S1, l1_cols, l1_vals, 16384, 2.f, 1);
    gemm1_mfma<<<V1q / 8, 256, 0, stream>>>(XS1, B1p, b1, XS2);

    // Chebyshev levels, conv2: 8 col-blocks x 1024 row-quads
    spmm_cheb<9, 10><<<8192, 256, 0, stream>>>(XS2, XS2, XS2 + S2, l2_cols, l2_vals, 8192, 1.f, 0);
    for (int k = 2; k < Kq; k++)
        spmm_cheb<9, 10><<<8192, 256, 0, stream>>>(XS2 + (size_t)(k - 1) * S2, XS2 + (size_t)(k - 2) * S2,
                                                   XS2 + (size_t)k * S2, l2_cols, l2_vals, 8192, 2.f, 1);
    gemm2_mfma<<<V2q / 16, 256, 0, stream>>>(XS2, B2p, b2, P2f);

    // FC: pack P to bf16 A-frags, stream W with in-register bf16 conversion + MFMA
    pack_p<<<512, 256, 0, stream>>>(P2f, Pp);
    fc_init<<<32, 256, 0, stream>>>(fcb, out);
    fc_mfma<<<dim3(32, 32), 256, 0, stream>>>(Pp, fcw, out);
}